// Round 8
// baseline (770.777 us; speedup 1.0000x reference)
//
#include <hip/hip_runtime.h>
#include <math.h>

#define N_NODES 50000
#define N_EDGES 800000
#define NODE_IN 36
#define EDGE_IN 16
#define C_HID 128
#define C_OUT 64
#define BN_EPS 1e-5f
#define SCAN_T 1024
#define CHUNK ((N_NODES + SCAN_T - 1) / SCAN_T)   // 49
#define DT_NT 32    // nodes per block in dense tiled kernels

typedef __attribute__((ext_vector_type(2))) float v2f;

__device__ __forceinline__ int rfl(int v) { return __builtin_amdgcn_readfirstlane(v); }

__device__ __forceinline__ v2f v2(float s) { v2f r; r.x = s; r.y = s; return r; }

// paired bf16: u32 = bf16(lo) | bf16(hi)<<16 ; lo = channel c, hi = channel c+64
__device__ __forceinline__ v2f unpack_bf2(unsigned u) {
    v2f r;
    r.x = __uint_as_float(u << 16);
    r.y = __uint_as_float(u & 0xFFFF0000u);
    return r;
}
__device__ __forceinline__ unsigned pack_bf2(float lo, float hi) {
    unsigned ul = __float_as_uint(lo); ul += 0x7FFF + ((ul >> 16) & 1);
    unsigned uh = __float_as_uint(hi); uh += 0x7FFF + ((uh >> 16) & 1);
    return (ul >> 16) | (uh & 0xFFFF0000u);
}

__device__ __forceinline__ v2f sel4v(int cat, v2f a, v2f b, v2f c, v2f d) {
    v2f r = (cat == 0) ? a : b;
    r = (cat == 2) ? c : r;
    r = (cat == 3) ? d : r;
    return r;
}
__device__ __forceinline__ float sel4(int cat, float a, float b, float c, float d) {
    float r = (cat == 0) ? a : b;
    r = (cat == 2) ? c : r;
    r = (cat == 3) ? d : r;
    return r;
}

// ================= node features =================
__global__ void k_node_feat(const int* __restrict__ xcat,
                            const float* __restrict__ xcont,
                            const float* __restrict__ node_emb,
                            float* __restrict__ x) {
    int idx = blockIdx.x * blockDim.x + threadIdx.x;
    if (idx >= N_NODES * NODE_IN) return;
    int i = idx / NODE_IN;
    int j = idx - i * NODE_IN;
    float v;
    if (j < 20) v = node_emb[xcat[i] * 20 + j];
    else        v = xcont[i * 16 + (j - 20)];
    x[idx] = v;
}

// ================= CSR build =================
__global__ void k_deg(const int* __restrict__ ei, int* __restrict__ deg) {
    int e = blockIdx.x * blockDim.x + threadIdx.x;
    if (e >= N_EDGES) return;
    atomicAdd(deg + ei[N_EDGES + e], 1);
}

__global__ void k_scan(const int* __restrict__ deg, int* __restrict__ rowp,
                       int* __restrict__ cursor) {
    __shared__ int sums[SCAN_T];
    int t = threadIdx.x;
    int lo = t * CHUNK, hi = min(lo + CHUNK, N_NODES);
    int s = 0;
    for (int i = lo; i < hi; i++) s += deg[i];
    sums[t] = s;
    __syncthreads();
    for (int off = 1; off < SCAN_T; off <<= 1) {
        int v = 0;
        if (t >= off) v = sums[t - off];
        __syncthreads();
        if (t >= off) sums[t] += v;
        __syncthreads();
    }
    int run = sums[t] - s;      // exclusive prefix
    for (int i = lo; i < hi; i++) {
        rowp[i] = run;
        cursor[i] = run;
        run += deg[i];
    }
    if (t == SCAN_T - 1) rowp[N_NODES] = sums[SCAN_T - 1];
}

// fill: interleaved meta record {eid, src|cat<<24}
__global__ void k_fill(const int* __restrict__ ei, const int* __restrict__ ecat,
                       int* __restrict__ cursor, int2* __restrict__ csr_m) {
    int e = blockIdx.x * blockDim.x + threadIdx.x;
    if (e >= N_EDGES) return;
    int d = ei[N_EDGES + e];
    int pos = atomicAdd(cursor + d, 1);
    csr_m[pos] = make_int2(e, ei[e] | (ecat[e] << 24));
}

// ======== GINE1 gather (F=36): 8-edge batches, loads grouped first ========
__global__ void k_gine1_gather(const int* __restrict__ rowp,
                               const int2* __restrict__ csr_m,
                               const float* __restrict__ econt,
                               const float* __restrict__ edge_emb,
                               const float* __restrict__ W,   // [16,36]
                               const float* __restrict__ b,   // [36]
                               const float* __restrict__ x,
                               float* __restrict__ agg) {
    int i = blockIdx.x * 4 + (threadIdx.x >> 6);
    int lane = threadIdx.x & 63;
    if (i >= N_NODES) return;
    int c = (lane < NODE_IN) ? lane : (NODE_IN - 1);
    float w[12];
#pragma unroll
    for (int k = 0; k < 12; k++) w[k] = W[(4 + k) * NODE_IN + c];
    float tb[4];
#pragma unroll
    for (int q = 0; q < 4; q++) {
        float v = b[c];
#pragma unroll
        for (int k = 0; k < 4; k++) v += edge_emb[q * 4 + k] * W[k * NODE_IN + c];
        tb[q] = v;
    }
    int beg = rfl(rowp[i]), end = rfl(rowp[i + 1]);
    float acc = 0.f;
    int p = beg;
    for (; p + 8 <= end; p += 8) {
        int eid[8], ps8[8];
#pragma unroll
        for (int q = 0; q < 8; q++) {
            int2 mm = csr_m[p + q];
            eid[q] = rfl(mm.x); ps8[q] = rfl(mm.y);
        }
        float xs[8];
#pragma unroll
        for (int q = 0; q < 8; q++)
            xs[q] = x[(size_t)(ps8[q] & 0xFFFFFF) * NODE_IN + c];
#pragma unroll
        for (int g = 0; g < 2; g++) {
#pragma unroll
            for (int bq = 0; bq < 4; bq++) {
                int idx = g * 4 + bq;
                const float4* ec4 = (const float4*)(econt + (size_t)eid[idx] * 12);
                float4 A = ec4[0], B = ec4[1], C4 = ec4[2];
                int cat = ps8[idx] >> 24;
                float t = sel4(cat, tb[0], tb[1], tb[2], tb[3]);
                t += A.x * w[0] + A.y * w[1] + A.z * w[2] + A.w * w[3];
                t += B.x * w[4] + B.y * w[5] + B.z * w[6] + B.w * w[7];
                t += C4.x * w[8] + C4.y * w[9] + C4.z * w[10] + C4.w * w[11];
                acc += fmaxf(xs[idx] + t, 0.f);
            }
        }
    }
    for (; p < end; ++p) {
        int2 mm = csr_m[p];
        int eid = rfl(mm.x), ps = rfl(mm.y);
        int src = ps & 0xFFFFFF, cat = ps >> 24;
        const float4* ec4 = (const float4*)(econt + (size_t)eid * 12);
        float4 A = ec4[0], B = ec4[1], C4 = ec4[2];
        float t = sel4(cat, tb[0], tb[1], tb[2], tb[3]);
        t += A.x * w[0] + A.y * w[1] + A.z * w[2] + A.w * w[3];
        t += B.x * w[4] + B.y * w[5] + B.z * w[6] + B.w * w[7];
        t += C4.x * w[8] + C4.y * w[9] + C4.z * w[10] + C4.w * w[11];
        acc += fmaxf(x[(size_t)src * NODE_IN + c] + t, 0.f);
    }
    if (lane < NODE_IN) agg[(size_t)i * NODE_IN + lane] = acc;
}

// ===== GINE1 node MLP + BN; OUTPUT h1 as paired bf16 (ch c | ch c+64) =====
__global__ __launch_bounds__(256, 4) void k_gine1_node(
        const float* __restrict__ x, const float* __restrict__ agg,
        const float* __restrict__ eps_p,
        const float* __restrict__ W,   // [36,128]
        const float* __restrict__ b, const float* __restrict__ g,
        const float* __restrict__ bb, const float* __restrict__ m,
        const float* __restrict__ v, unsigned* __restrict__ h1p) {
    __shared__ float sW[NODE_IN * C_HID];     // 18 KB
    __shared__ float sz[DT_NT * NODE_IN];     // 4.5 KB
    int tid = threadIdx.x;
    int node0 = blockIdx.x * DT_NT;
    float eps = eps_p[0];
    {
        const float4* Wv = (const float4*)W;
        float4* sWv = (float4*)sW;
        for (int t = tid; t < NODE_IN * C_HID / 4; t += 256) sWv[t] = Wv[t];
    }
    {
        int nmax = min(DT_NT, N_NODES - node0);
        int tot = nmax * NODE_IN / 4;
        const float4* xv = (const float4*)(x + (size_t)node0 * NODE_IN);
        const float4* av = (const float4*)(agg + (size_t)node0 * NODE_IN);
        float4* szv = (float4*)sz;
        float s = 1.f + eps;
        for (int t = tid; t < tot; t += 256) {
            float4 a = xv[t], c = av[t];
            float4 r;
            r.x = s * a.x + c.x; r.y = s * a.y + c.y;
            r.z = s * a.z + c.z; r.w = s * a.w + c.w;
            szv[t] = r;
        }
    }
    __syncthreads();
    int cg = tid & 15, c0 = cg * 4;           // pair base (lo channels c0..c0+3)
    int n0 = (tid >> 4) * 2;                  // 2 nodes per thread
    float4 bL = *(const float4*)&b[c0];
    float4 bH = *(const float4*)&b[c0 + 64];
    float accL[2][4], accH[2][4];
#pragma unroll
    for (int n = 0; n < 2; n++) {
        accL[n][0] = bL.x; accL[n][1] = bL.y; accL[n][2] = bL.z; accL[n][3] = bL.w;
        accH[n][0] = bH.x; accH[n][1] = bH.y; accH[n][2] = bH.z; accH[n][3] = bH.w;
    }
#pragma unroll 2
    for (int jb = 0; jb < NODE_IN; jb += 4) {
#pragma unroll
        for (int r = 0; r < 4; r++) {
            float4 wl = *(const float4*)&sW[(jb + r) * C_HID + c0];
            float4 wh = *(const float4*)&sW[(jb + r) * C_HID + c0 + 64];
#pragma unroll
            for (int n = 0; n < 2; n++) {
                float zz = sz[(n0 + n) * NODE_IN + jb + r];
                accL[n][0] += zz * wl.x; accL[n][1] += zz * wl.y;
                accL[n][2] += zz * wl.z; accL[n][3] += zz * wl.w;
                accH[n][0] += zz * wh.x; accH[n][1] += zz * wh.y;
                accH[n][2] += zz * wh.z; accH[n][3] += zz * wh.w;
            }
        }
    }
    float4 gL = *(const float4*)&g[c0],  gH = *(const float4*)&g[c0 + 64];
    float4 mL = *(const float4*)&m[c0],  mH = *(const float4*)&m[c0 + 64];
    float4 vL = *(const float4*)&v[c0],  vH = *(const float4*)&v[c0 + 64];
    float4 bbL = *(const float4*)&bb[c0], bbH = *(const float4*)&bb[c0 + 64];
    float scL[4] = { gL.x * rsqrtf(vL.x + BN_EPS), gL.y * rsqrtf(vL.y + BN_EPS),
                     gL.z * rsqrtf(vL.z + BN_EPS), gL.w * rsqrtf(vL.w + BN_EPS) };
    float scH[4] = { gH.x * rsqrtf(vH.x + BN_EPS), gH.y * rsqrtf(vH.y + BN_EPS),
                     gH.z * rsqrtf(vH.z + BN_EPS), gH.w * rsqrtf(vH.w + BN_EPS) };
    float mLa[4] = { mL.x, mL.y, mL.z, mL.w }, mHa[4] = { mH.x, mH.y, mH.z, mH.w };
    float bbLa[4] = { bbL.x, bbL.y, bbL.z, bbL.w }, bbHa[4] = { bbH.x, bbH.y, bbH.z, bbH.w };
#pragma unroll
    for (int n = 0; n < 2; n++) {
        int i = node0 + n0 + n;
        if (i < N_NODES) {
            uint4 o;
            unsigned* po = (unsigned*)&o;
#pragma unroll
            for (int k = 0; k < 4; k++) {
                float lo = (fmaxf(accL[n][k], 0.f) - mLa[k]) * scL[k] + bbLa[k];
                float hi = (fmaxf(accH[n][k], 0.f) - mHa[k]) * scH[k] + bbHa[k];
                po[k] = pack_bf2(lo, hi);
            }
            *(uint4*)&h1p[(size_t)i * 64 + c0] = o;
        }
    }
}

// ======== GINE2 gather: 8-edge batches, paired bf16 h1, packed math ========
__global__ void k_gine2_gather(const int* __restrict__ rowp,
                               const int2* __restrict__ csr_m,
                               const float* __restrict__ econt,
                               const float* __restrict__ edge_emb,
                               const float* __restrict__ W,   // [16,128]
                               const float* __restrict__ b,   // [128]
                               const unsigned* __restrict__ h1p,
                               float2* __restrict__ aggp) {
    int i = blockIdx.x * 4 + (threadIdx.x >> 6);
    int lane = threadIdx.x & 63;
    if (i >= N_NODES) return;
    v2f w01[12];
#pragma unroll
    for (int k = 0; k < 12; k++) {
        w01[k].x = W[(4 + k) * C_HID + lane];
        w01[k].y = W[(4 + k) * C_HID + lane + 64];
    }
    v2f tb01[4];
#pragma unroll
    for (int q = 0; q < 4; q++) {
        v2f t; t.x = b[lane]; t.y = b[lane + 64];
#pragma unroll
        for (int k = 0; k < 4; k++) {
            float ev = edge_emb[q * 4 + k];
            t.x += ev * W[k * C_HID + lane];
            t.y += ev * W[k * C_HID + lane + 64];
        }
        tb01[q] = t;
    }
    const v2f zero = v2(0.f);
    int beg = rfl(rowp[i]), end = rfl(rowp[i + 1]);
    v2f acc01 = zero;
    int p = beg;
    for (; p + 8 <= end; p += 8) {
        int eid[8], ps8[8];
#pragma unroll
        for (int q = 0; q < 8; q++) {
            int2 mm = csr_m[p + q];
            eid[q] = rfl(mm.x); ps8[q] = rfl(mm.y);
        }
        v2f xs[8];
#pragma unroll
        for (int q = 0; q < 8; q++)
            xs[q] = unpack_bf2(h1p[(size_t)(ps8[q] & 0xFFFFFF) * 64 + lane]);
#pragma unroll
        for (int g = 0; g < 2; g++) {
#pragma unroll
            for (int bq = 0; bq < 4; bq++) {
                int idx = g * 4 + bq;
                const float4* ec4 = (const float4*)(econt + (size_t)eid[idx] * 12);
                float4 A = ec4[0], B = ec4[1], C4 = ec4[2];
                int cat = ps8[idx] >> 24;
                v2f t = sel4v(cat, tb01[0], tb01[1], tb01[2], tb01[3]);
                t = __builtin_elementwise_fma(v2(A.x), w01[0], t);
                t = __builtin_elementwise_fma(v2(A.y), w01[1], t);
                t = __builtin_elementwise_fma(v2(A.z), w01[2], t);
                t = __builtin_elementwise_fma(v2(A.w), w01[3], t);
                t = __builtin_elementwise_fma(v2(B.x), w01[4], t);
                t = __builtin_elementwise_fma(v2(B.y), w01[5], t);
                t = __builtin_elementwise_fma(v2(B.z), w01[6], t);
                t = __builtin_elementwise_fma(v2(B.w), w01[7], t);
                t = __builtin_elementwise_fma(v2(C4.x), w01[8], t);
                t = __builtin_elementwise_fma(v2(C4.y), w01[9], t);
                t = __builtin_elementwise_fma(v2(C4.z), w01[10], t);
                t = __builtin_elementwise_fma(v2(C4.w), w01[11], t);
                acc01 += __builtin_elementwise_max(xs[idx] + t, zero);
            }
        }
    }
    for (; p < end; ++p) {
        int2 mm = csr_m[p];
        int eid = rfl(mm.x), ps = rfl(mm.y);
        int src = ps & 0xFFFFFF, cat = ps >> 24;
        const float4* ec4 = (const float4*)(econt + (size_t)eid * 12);
        float4 A = ec4[0], B = ec4[1], C4 = ec4[2];
        v2f xs = unpack_bf2(h1p[(size_t)src * 64 + lane]);
        v2f t = sel4v(cat, tb01[0], tb01[1], tb01[2], tb01[3]);
        t = __builtin_elementwise_fma(v2(A.x), w01[0], t);
        t = __builtin_elementwise_fma(v2(A.y), w01[1], t);
        t = __builtin_elementwise_fma(v2(A.z), w01[2], t);
        t = __builtin_elementwise_fma(v2(A.w), w01[3], t);
        t = __builtin_elementwise_fma(v2(B.x), w01[4], t);
        t = __builtin_elementwise_fma(v2(B.y), w01[5], t);
        t = __builtin_elementwise_fma(v2(B.z), w01[6], t);
        t = __builtin_elementwise_fma(v2(B.w), w01[7], t);
        t = __builtin_elementwise_fma(v2(C4.x), w01[8], t);
        t = __builtin_elementwise_fma(v2(C4.y), w01[9], t);
        t = __builtin_elementwise_fma(v2(C4.z), w01[10], t);
        t = __builtin_elementwise_fma(v2(C4.w), w01[11], t);
        acc01 += __builtin_elementwise_max(xs + t, zero);
    }
    float2 o; o.x = acc01.x; o.y = acc01.y;
    aggp[(size_t)i * 64 + lane] = o;
}

// ===== GINE2 node MLP + BN; h1 paired bf16 + agg paired fp32 in, h2 standard out =====
__global__ __launch_bounds__(256, 4) void k_gine2_node(
        const unsigned* __restrict__ h1p, const float2* __restrict__ aggp,
        const float* __restrict__ eps_p,
        const float* __restrict__ W,   // [128,128]
        const float* __restrict__ b, const float* __restrict__ g,
        const float* __restrict__ bb, const float* __restrict__ m,
        const float* __restrict__ v, float* __restrict__ h2) {
    __shared__ float sW[64 * C_HID];          // 32 KB (half of W)
    __shared__ float sz[DT_NT * C_HID];       // 16 KB
    int tid = threadIdx.x;
    int node0 = blockIdx.x * DT_NT;
    float eps = eps_p[0];
    {
        int nmax = min(DT_NT, N_NODES - node0);
        int tot = nmax * 64;                  // pairs
        float s = 1.f + eps;
        for (int t = tid; t < tot; t += 256) {
            int n = t >> 6, pp = t & 63;
            v2f h = unpack_bf2(h1p[(size_t)(node0 + n) * 64 + pp]);
            float2 a = aggp[(size_t)(node0 + n) * 64 + pp];
            sz[n * C_HID + pp]      = s * h.x + a.x;
            sz[n * C_HID + pp + 64] = s * h.y + a.y;
        }
    }
    int cg = tid & 31, c0 = cg * 4;
    int n0 = (tid >> 5) * 4;
    float4 bi = *(const float4*)&b[c0];
    float acc[4][4];
#pragma unroll
    for (int n = 0; n < 4; n++) {
        acc[n][0] = bi.x; acc[n][1] = bi.y; acc[n][2] = bi.z; acc[n][3] = bi.w;
    }
    for (int half = 0; half < 2; half++) {
        __syncthreads();
        {
            const float4* Wv = (const float4*)(W + half * 64 * C_HID);
            float4* sWv = (float4*)sW;
            for (int t = tid; t < 64 * C_HID / 4; t += 256) sWv[t] = Wv[t];
        }
        __syncthreads();
        int jbase = half * 64;
#pragma unroll 2
        for (int jb = 0; jb < 64; jb += 4) {
            float4 w0 = *(const float4*)&sW[(jb + 0) * C_HID + c0];
            float4 w1 = *(const float4*)&sW[(jb + 1) * C_HID + c0];
            float4 w2 = *(const float4*)&sW[(jb + 2) * C_HID + c0];
            float4 w3 = *(const float4*)&sW[(jb + 3) * C_HID + c0];
#pragma unroll
            for (int n = 0; n < 4; n++) {
                float4 zz = *(const float4*)&sz[(n0 + n) * C_HID + jbase + jb];
                acc[n][0] += zz.x * w0.x + zz.y * w1.x + zz.z * w2.x + zz.w * w3.x;
                acc[n][1] += zz.x * w0.y + zz.y * w1.y + zz.z * w2.y + zz.w * w3.y;
                acc[n][2] += zz.x * w0.z + zz.y * w1.z + zz.z * w2.z + zz.w * w3.z;
                acc[n][3] += zz.x * w0.w + zz.y * w1.w + zz.z * w2.w + zz.w * w3.w;
            }
        }
    }
    float4 gg = *(const float4*)&g[c0];
    float4 mm = *(const float4*)&m[c0];
    float4 vv = *(const float4*)&v[c0];
    float4 bbv = *(const float4*)&bb[c0];
    float4 sc;
    sc.x = gg.x * rsqrtf(vv.x + BN_EPS); sc.y = gg.y * rsqrtf(vv.y + BN_EPS);
    sc.z = gg.z * rsqrtf(vv.z + BN_EPS); sc.w = gg.w * rsqrtf(vv.w + BN_EPS);
#pragma unroll
    for (int n = 0; n < 4; n++) {
        int i = node0 + n0 + n;
        if (i < N_NODES) {
            float4 o;
            o.x = (fmaxf(acc[n][0], 0.f) - mm.x) * sc.x + bbv.x;
            o.y = (fmaxf(acc[n][1], 0.f) - mm.y) * sc.y + bbv.y;
            o.z = (fmaxf(acc[n][2], 0.f) - mm.z) * sc.z + bbv.z;
            o.w = (fmaxf(acc[n][3], 0.f) - mm.w) * sc.w + bbv.w;
            *(float4*)&h2[(size_t)i * C_HID + c0] = o;
        }
    }
}

// ===== mean edge feature =====
__global__ void k_ea_sum(const int* __restrict__ ecat,
                         const float* __restrict__ econt,
                         float* __restrict__ ea_sum) {   // [0..11] cont, [12..15] counts
    float p[12];
#pragma unroll
    for (int k = 0; k < 12; k++) p[k] = 0.f;
    float cnt[4] = {0.f, 0.f, 0.f, 0.f};
    int stride = gridDim.x * blockDim.x;
    for (int e = blockIdx.x * blockDim.x + threadIdx.x; e < N_EDGES; e += stride) {
        int c = ecat[e];
        cnt[0] += (c == 0) ? 1.f : 0.f;
        cnt[1] += (c == 1) ? 1.f : 0.f;
        cnt[2] += (c == 2) ? 1.f : 0.f;
        cnt[3] += (c == 3) ? 1.f : 0.f;
        const float4* v4 = (const float4*)(econt + (size_t)e * 12);
        float4 a = v4[0], bq = v4[1], d = v4[2];
        p[0] += a.x;  p[1] += a.y;  p[2] += a.z;  p[3] += a.w;
        p[4] += bq.x; p[5] += bq.y; p[6] += bq.z; p[7] += bq.w;
        p[8] += d.x;  p[9] += d.y;  p[10] += d.z; p[11] += d.w;
    }
    float vals[16];
#pragma unroll
    for (int k = 0; k < 12; k++) vals[k] = p[k];
#pragma unroll
    for (int k = 0; k < 4; k++) vals[12 + k] = cnt[k];
#pragma unroll
    for (int k = 0; k < 16; k++) {
        float v = vals[k];
#pragma unroll
        for (int off = 32; off > 0; off >>= 1) v += __shfl_xor(v, off);
        vals[k] = v;
    }
    __shared__ float red[4][16];
    int wid = threadIdx.x >> 6, lane = threadIdx.x & 63;
    if (lane == 0) {
#pragma unroll
        for (int k = 0; k < 16; k++) red[wid][k] = vals[k];
    }
    __syncthreads();
    if (threadIdx.x < 16) {
        float s = red[0][threadIdx.x] + red[1][threadIdx.x] +
                  red[2][threadIdx.x] + red[3][threadIdx.x];
        atomicAdd(ea_sum + threadIdx.x, s);
    }
}

__global__ void k_loop_prep(const float* __restrict__ ea_sum,
                            const float* __restrict__ edge_emb,
                            const float* __restrict__ We,
                            float* __restrict__ ee_loop) {
    int c = threadIdx.x;
    const float inv = 1.f / (float)N_EDGES;
    float acc = 0.f;
#pragma unroll
    for (int k = 0; k < 4; k++) {
        float s = 0.f;
#pragma unroll
        for (int q = 0; q < 4; q++) s += ea_sum[12 + q] * edge_emb[q * 4 + k];
        acc += (s * inv) * We[k * C_HID + c];
    }
#pragma unroll
    for (int k = 0; k < 12; k++)
        acc += (ea_sum[k] * inv) * We[(4 + k) * C_HID + c];
    ee_loop[c] = acc;
}

// ===== GAT node transforms: xl paired bf16, xr paired fp32 =====
__global__ __launch_bounds__(256, 4) void k_gat0(
        const float* __restrict__ h2,
        const float* __restrict__ Wl, const float* __restrict__ bl,
        const float* __restrict__ Wr, const float* __restrict__ br,
        unsigned* __restrict__ xlp, float2* __restrict__ xrp) {
    __shared__ float sW[64 * C_HID];          // 32 KB
    __shared__ float sz[DT_NT * C_HID];       // 16 KB
    int tid = threadIdx.x;
    int node0 = blockIdx.x * DT_NT;
    {
        int nmax = min(DT_NT, N_NODES - node0);
        int tot = nmax * C_HID / 4;
        const float4* hv = (const float4*)(h2 + (size_t)node0 * C_HID);
        float4* szv = (float4*)sz;
        for (int t = tid; t < tot; t += 256) szv[t] = hv[t];
    }
    int cg = tid & 15, c0 = cg * 4;           // pair base
    int n0 = (tid >> 4) * 2;                  // 2 nodes
    for (int wsel = 0; wsel < 2; wsel++) {
        const float* Wm = wsel ? Wr : Wl;
        const float* bm = wsel ? br : bl;
        float4 bL = *(const float4*)&bm[c0];
        float4 bH = *(const float4*)&bm[c0 + 64];
        float accL[2][4], accH[2][4];
#pragma unroll
        for (int n = 0; n < 2; n++) {
            accL[n][0] = bL.x; accL[n][1] = bL.y; accL[n][2] = bL.z; accL[n][3] = bL.w;
            accH[n][0] = bH.x; accH[n][1] = bH.y; accH[n][2] = bH.z; accH[n][3] = bH.w;
        }
        for (int half = 0; half < 2; half++) {
            __syncthreads();
            {
                const float4* Wv = (const float4*)(Wm + half * 64 * C_HID);
                float4* sWv = (float4*)sW;
                for (int t = tid; t < 64 * C_HID / 4; t += 256) sWv[t] = Wv[t];
            }
            __syncthreads();
            int jbase = half * 64;
#pragma unroll 2
            for (int jb = 0; jb < 64; jb += 4) {
#pragma unroll
                for (int r = 0; r < 4; r++) {
                    float4 wl = *(const float4*)&sW[(jb + r) * C_HID + c0];
                    float4 wh = *(const float4*)&sW[(jb + r) * C_HID + c0 + 64];
#pragma unroll
                    for (int n = 0; n < 2; n++) {
                        float zz = sz[(n0 + n) * C_HID + jbase + jb + r];
                        accL[n][0] += zz * wl.x; accL[n][1] += zz * wl.y;
                        accL[n][2] += zz * wl.z; accL[n][3] += zz * wl.w;
                        accH[n][0] += zz * wh.x; accH[n][1] += zz * wh.y;
                        accH[n][2] += zz * wh.z; accH[n][3] += zz * wh.w;
                    }
                }
            }
        }
#pragma unroll
        for (int n = 0; n < 2; n++) {
            int i = node0 + n0 + n;
            if (i < N_NODES) {
                if (wsel == 0) {
                    uint4 o;
                    unsigned* po = (unsigned*)&o;
#pragma unroll
                    for (int k = 0; k < 4; k++) po[k] = pack_bf2(accL[n][k], accH[n][k]);
                    *(uint4*)&xlp[(size_t)i * 64 + c0] = o;
                } else {
                    float4 o1, o2;
                    o1.x = accL[n][0]; o1.y = accH[n][0]; o1.z = accL[n][1]; o1.w = accH[n][1];
                    o2.x = accL[n][2]; o2.y = accH[n][2]; o2.z = accL[n][3]; o2.w = accH[n][3];
                    *(float4*)&xrp[(size_t)i * 64 + c0] = o1;
                    *(float4*)&xrp[(size_t)i * 64 + c0 + 2] = o2;
                }
            }
        }
    }
}

// ===== GAT fused: 8-edge batches, plain-exp softmax, packed math =====
__global__ void k_gat_fused(const int* __restrict__ rowp,
                            const int2* __restrict__ csr_m,
                            const float* __restrict__ econt,
                            const float* __restrict__ edge_emb,
                            const float* __restrict__ We,    // [16,128]
                            const float* __restrict__ att,   // [128]
                            const float* __restrict__ ee_loop,
                            const unsigned* __restrict__ xlp,
                            const float2* __restrict__ xrp,
                            const float* __restrict__ bias,  // [64]
                            float* __restrict__ out) {
    int i = blockIdx.x * 4 + (threadIdx.x >> 6);
    int lane = threadIdx.x & 63;
    if (i >= N_NODES) return;
    v2f w01[12];
#pragma unroll
    for (int k = 0; k < 12; k++) {
        w01[k].x = We[(4 + k) * C_HID + lane];
        w01[k].y = We[(4 + k) * C_HID + lane + 64];
    }
    v2f tb01[4];
#pragma unroll
    for (int q = 0; q < 4; q++) {
        v2f t = v2(0.f);
#pragma unroll
        for (int k = 0; k < 4; k++) {
            float ev = edge_emb[q * 4 + k];
            t.x += ev * We[k * C_HID + lane];
            t.y += ev * We[k * C_HID + lane + 64];
        }
        tb01[q] = t;
    }
    v2f at01; at01.x = att[lane]; at01.y = att[lane + 64];
    v2f lp01; lp01.x = ee_loop[lane]; lp01.y = ee_loop[lane + 64];
    const v2f zero = v2(0.f);
    const v2f fifth = v2(0.2f);

    float2 xr2 = xrp[(size_t)i * 64 + lane];
    v2f xr01; xr01.x = xr2.x; xr01.y = xr2.y;
    v2f xld01 = unpack_bf2(xlp[(size_t)i * 64 + lane]);

    // self-loop alpha (plain exp — alphas are bounded, fp32-safe)
    v2f z01 = xld01 + xr01 + lp01;
    z01 = __builtin_elementwise_max(z01, zero) +
          fifth * __builtin_elementwise_min(z01, zero);
    v2f d01 = z01 * at01;
#pragma unroll
    for (int off = 32; off > 0; off >>= 1) {
        v2f t;
        t.x = __shfl_xor(d01.x, off);
        t.y = __shfl_xor(d01.y, off);
        d01 += t;
    }
    v2f den01; den01.x = __expf(d01.x); den01.y = __expf(d01.y);
    v2f acc01 = xld01 * den01;

    int beg = rfl(rowp[i]), end = rfl(rowp[i + 1]);
    int p = beg;
    for (; p + 8 <= end; p += 8) {
        int eid[8], ps8[8];
#pragma unroll
        for (int q = 0; q < 8; q++) {
            int2 mm = csr_m[p + q];
            eid[q] = rfl(mm.x); ps8[q] = rfl(mm.y);
        }
        v2f xs[8];
#pragma unroll
        for (int q = 0; q < 8; q++)
            xs[q] = unpack_bf2(xlp[(size_t)(ps8[q] & 0xFFFFFF) * 64 + lane]);
#pragma unroll
        for (int g = 0; g < 2; g++) {
            v2f dd[4];
#pragma unroll
            for (int bq = 0; bq < 4; bq++) {
                int idx = g * 4 + bq;
                const float4* ec4 = (const float4*)(econt + (size_t)eid[idx] * 12);
                float4 A = ec4[0], B = ec4[1], C4 = ec4[2];
                int cat = ps8[idx] >> 24;
                v2f e = sel4v(cat, tb01[0], tb01[1], tb01[2], tb01[3]);
                e = __builtin_elementwise_fma(v2(A.x), w01[0], e);
                e = __builtin_elementwise_fma(v2(A.y), w01[1], e);
                e = __builtin_elementwise_fma(v2(A.z), w01[2], e);
                e = __builtin_elementwise_fma(v2(A.w), w01[3], e);
                e = __builtin_elementwise_fma(v2(B.x), w01[4], e);
                e = __builtin_elementwise_fma(v2(B.y), w01[5], e);
                e = __builtin_elementwise_fma(v2(B.z), w01[6], e);
                e = __builtin_elementwise_fma(v2(B.w), w01[7], e);
                e = __builtin_elementwise_fma(v2(C4.x), w01[8], e);
                e = __builtin_elementwise_fma(v2(C4.y), w01[9], e);
                e = __builtin_elementwise_fma(v2(C4.z), w01[10], e);
                e = __builtin_elementwise_fma(v2(C4.w), w01[11], e);
                v2f z = xs[idx] + xr01 + e;
                z = __builtin_elementwise_max(z, zero) +
                    fifth * __builtin_elementwise_min(z, zero);
                dd[bq] = z * at01;
            }
#pragma unroll
            for (int off = 32; off > 0; off >>= 1) {
#pragma unroll
                for (int bq = 0; bq < 4; bq++) {
                    v2f t;
                    t.x = __shfl_xor(dd[bq].x, off);
                    t.y = __shfl_xor(dd[bq].y, off);
                    dd[bq] += t;
                }
            }
            v2f p0; p0.x = __expf(dd[0].x); p0.y = __expf(dd[0].y);
            v2f p1; p1.x = __expf(dd[1].x); p1.y = __expf(dd[1].y);
            v2f p2; p2.x = __expf(dd[2].x); p2.y = __expf(dd[2].y);
            v2f p3; p3.x = __expf(dd[3].x); p3.y = __expf(dd[3].y);
            den01 += (p0 + p1) + (p2 + p3);
            acc01 = __builtin_elementwise_fma(p0, xs[g * 4 + 0], acc01);
            acc01 = __builtin_elementwise_fma(p1, xs[g * 4 + 1], acc01);
            acc01 = __builtin_elementwise_fma(p2, xs[g * 4 + 2], acc01);
            acc01 = __builtin_elementwise_fma(p3, xs[g * 4 + 3], acc01);
        }
    }
    for (; p < end; ++p) {
        int2 mm = csr_m[p];
        int eid = rfl(mm.x), ps = rfl(mm.y);
        int src = ps & 0xFFFFFF, cat = ps >> 24;
        const float4* ec4 = (const float4*)(econt + (size_t)eid * 12);
        float4 A = ec4[0], B = ec4[1], C4 = ec4[2];
        v2f xs = unpack_bf2(xlp[(size_t)src * 64 + lane]);
        v2f e = sel4v(cat, tb01[0], tb01[1], tb01[2], tb01[3]);
        e = __builtin_elementwise_fma(v2(A.x), w01[0], e);
        e = __builtin_elementwise_fma(v2(A.y), w01[1], e);
        e = __builtin_elementwise_fma(v2(A.z), w01[2], e);
        e = __builtin_elementwise_fma(v2(A.w), w01[3], e);
        e = __builtin_elementwise_fma(v2(B.x), w01[4], e);
        e = __builtin_elementwise_fma(v2(B.y), w01[5], e);
        e = __builtin_elementwise_fma(v2(B.z), w01[6], e);
        e = __builtin_elementwise_fma(v2(B.w), w01[7], e);
        e = __builtin_elementwise_fma(v2(C4.x), w01[8], e);
        e = __builtin_elementwise_fma(v2(C4.y), w01[9], e);
        e = __builtin_elementwise_fma(v2(C4.z), w01[10], e);
        e = __builtin_elementwise_fma(v2(C4.w), w01[11], e);
        v2f z = xs + xr01 + e;
        z = __builtin_elementwise_max(z, zero) +
            fifth * __builtin_elementwise_min(z, zero);
        v2f a = z * at01;
#pragma unroll
        for (int off = 32; off > 0; off >>= 1) {
            v2f t;
            t.x = __shfl_xor(a.x, off);
            t.y = __shfl_xor(a.y, off);
            a += t;
        }
        v2f pe; pe.x = __expf(a.x); pe.y = __expf(a.y);
        den01 += pe;
        acc01 = __builtin_elementwise_fma(pe, xs, acc01);
    }
    out[(size_t)i * C_OUT + lane] =
        0.5f * (acc01.x / den01.x + acc01.y / den01.y) + bias[lane];
}

extern "C" void kernel_launch(void* const* d_in, const int* in_sizes, int n_in,
                              void* d_out, int out_size, void* d_ws, size_t ws_size,
                              hipStream_t stream) {
    const int*   x_cat    = (const int*)d_in[0];
    const float* x_cont   = (const float*)d_in[1];
    const int*   e_cat    = (const int*)d_in[2];
    const float* e_cont   = (const float*)d_in[3];
    const int*   ei       = (const int*)d_in[4];
    const float* node_emb = (const float*)d_in[5];
    const float* edge_emb = (const float*)d_in[6];
    const float* eps1     = (const float*)d_in[7];
    const float* W1e      = (const float*)d_in[8];
    const float* b1e      = (const float*)d_in[9];
    const float* W1n      = (const float*)d_in[10];
    const float* b1n      = (const float*)d_in[11];
    const float* g1       = (const float*)d_in[12];
    const float* bb1      = (const float*)d_in[13];
    const float* m1       = (const float*)d_in[14];
    const float* v1       = (const float*)d_in[15];
    const float* eps2     = (const float*)d_in[16];
    const float* W2e      = (const float*)d_in[17];
    const float* b2e      = (const float*)d_in[18];
    const float* W2n      = (const float*)d_in[19];
    const float* b2n      = (const float*)d_in[20];
    const float* g2       = (const float*)d_in[21];
    const float* bb2      = (const float*)d_in[22];
    const float* m2       = (const float*)d_in[23];
    const float* v2p      = (const float*)d_in[24];
    const float* Wl       = (const float*)d_in[25];
    const float* bl       = (const float*)d_in[26];
    const float* Wr       = (const float*)d_in[27];
    const float* br       = (const float*)d_in[28];
    const float* Weg      = (const float*)d_in[29];
    const float* att      = (const float*)d_in[30];
    const float* gbias    = (const float*)d_in[31];

    const size_t NF128 = (size_t)N_NODES * C_HID;

    // layout: A (fp32, x -> h2) | B (fp32, agg36 / agg-pairs / xr-pairs) | Hb (bf16 pairs)
    float* A = (float*)d_ws;                 // N*128 floats
    float* B = A + NF128;                    // N*128 floats
    unsigned* Hb = (unsigned*)(B + NF128);   // N*64 u32
    float* ea_sum  = (float*)(Hb + (size_t)N_NODES * 64);   // 16
    float* ee_loop = ea_sum + 16;            // 128
    int2* csr_m  = (int2*)(ee_loop + C_HID); // E int2 (8B-aligned: even float count)
    int* deg     = (int*)(csr_m + N_EDGES);  // N
    int* cursor  = deg + N_NODES;            // N
    int* rowp    = cursor + N_NODES;         // N+1

    float* x = A;                 // N*36 (dead before h2 written)
    float* h2 = A;
    float* agg36 = B;
    float2* aggp = (float2*)B;    // N*64 float2
    float2* xrp  = (float2*)B;
    unsigned* h1p = Hb; unsigned* xlp = Hb;

    size_t need = (size_t)((char*)(rowp + N_NODES + 1) - (char*)d_ws);
    if (ws_size < need) return;

    hipMemsetAsync(deg, 0, N_NODES * sizeof(int), stream);
    hipMemsetAsync(ea_sum, 0, 16 * sizeof(float), stream);

    const int EB = (N_EDGES + 255) / 256;
    const int NB4 = (N_NODES + 3) / 4;
    const int NBD = (N_NODES + DT_NT - 1) / DT_NT;

    k_node_feat<<<(N_NODES * NODE_IN + 255) / 256, 256, 0, stream>>>(
        x_cat, x_cont, node_emb, x);
    k_deg<<<EB, 256, 0, stream>>>(ei, deg);
    k_scan<<<1, SCAN_T, 0, stream>>>(deg, rowp, cursor);
    k_fill<<<EB, 256, 0, stream>>>(ei, e_cat, cursor, csr_m);

    k_gine1_gather<<<NB4, 256, 0, stream>>>(
        rowp, csr_m, e_cont, edge_emb, W1e, b1e, x, agg36);
    k_gine1_node<<<NBD, 256, 0, stream>>>(
        x, agg36, eps1, W1n, b1n, g1, bb1, m1, v1, h1p);
    k_gine2_gather<<<NB4, 256, 0, stream>>>(
        rowp, csr_m, e_cont, edge_emb, W2e, b2e, h1p, aggp);
    k_gine2_node<<<NBD, 256, 0, stream>>>(
        h1p, aggp, eps2, W2n, b2n, g2, bb2, m2, v2p, h2);

    k_ea_sum<<<512, 256, 0, stream>>>(e_cat, e_cont, ea_sum);
    k_loop_prep<<<1, C_HID, 0, stream>>>(ea_sum, edge_emb, Weg, ee_loop);

    k_gat0<<<NBD, 256, 0, stream>>>(h2, Wl, bl, Wr, br, xlp, xrp);
    k_gat_fused<<<NB4, 256, 0, stream>>>(
        rowp, csr_m, e_cont, edge_emb, Weg, att, ee_loop,
        xlp, xrp, gbias, (float*)d_out);
}

// Round 9
// 700.691 us; speedup vs baseline: 1.1000x; 1.1000x over previous
//
#include <hip/hip_runtime.h>
#include <math.h>

#define N_NODES 50000
#define N_EDGES 800000
#define NODE_IN 36
#define EDGE_IN 16
#define C_HID 128
#define C_OUT 64
#define BN_EPS 1e-5f
#define SCAN_T 1024
#define CHUNK ((N_NODES + SCAN_T - 1) / SCAN_T)   // 49
#define DT_NT 32    // nodes per block in dense tiled kernels

// k_prep block-range split
#define NF_BLOCKS ((N_NODES * NODE_IN + 255) / 256)   // 7032
#define DEG_BLOCKS ((N_EDGES + 255) / 256)            // 3125
#define EAS_BLOCKS 512

typedef __attribute__((ext_vector_type(2))) float v2f;

__device__ __forceinline__ int rfl(int v) { return __builtin_amdgcn_readfirstlane(v); }

__device__ __forceinline__ v2f v2(float s) { v2f r; r.x = s; r.y = s; return r; }

// paired bf16: u32 = bf16(lo) | bf16(hi)<<16 ; lo = channel c, hi = channel c+64
__device__ __forceinline__ v2f unpack_bf2(unsigned u) {
    v2f r;
    r.x = __uint_as_float(u << 16);
    r.y = __uint_as_float(u & 0xFFFF0000u);
    return r;
}
__device__ __forceinline__ unsigned pack_bf2(float lo, float hi) {
    unsigned ul = __float_as_uint(lo); ul += 0x7FFF + ((ul >> 16) & 1);
    unsigned uh = __float_as_uint(hi); uh += 0x7FFF + ((uh >> 16) & 1);
    return (ul >> 16) | (uh & 0xFFFF0000u);
}

__device__ __forceinline__ v2f sel4v(int cat, v2f a, v2f b, v2f c, v2f d) {
    v2f r = (cat == 0) ? a : b;
    r = (cat == 2) ? c : r;
    r = (cat == 3) ? d : r;
    return r;
}
__device__ __forceinline__ float sel4(int cat, float a, float b, float c, float d) {
    float r = (cat == 0) ? a : b;
    r = (cat == 2) ? c : r;
    r = (cat == 3) ? d : r;
    return r;
}

// ===== fused prep: node features | degree histogram | edge-attr mean-sum =====
__global__ void k_prep(const int* __restrict__ xcat,
                       const float* __restrict__ xcont,
                       const float* __restrict__ node_emb,
                       const int* __restrict__ ei,
                       const int* __restrict__ ecat,
                       const float* __restrict__ econt,
                       float* __restrict__ x,
                       int* __restrict__ deg,
                       float* __restrict__ ea_sum) {
    int bb = blockIdx.x;
    if (bb < NF_BLOCKS) {
        int idx = bb * 256 + threadIdx.x;
        if (idx >= N_NODES * NODE_IN) return;
        int i = idx / NODE_IN;
        int j = idx - i * NODE_IN;
        float v;
        if (j < 20) v = node_emb[xcat[i] * 20 + j];
        else        v = xcont[i * 16 + (j - 20)];
        x[idx] = v;
        return;
    }
    if (bb < NF_BLOCKS + DEG_BLOCKS) {
        int e = (bb - NF_BLOCKS) * 256 + threadIdx.x;
        if (e >= N_EDGES) return;
        atomicAdd(deg + ei[N_EDGES + e], 1);
        return;
    }
    // ea_sum part
    int blk = bb - NF_BLOCKS - DEG_BLOCKS;
    float p[12];
#pragma unroll
    for (int k = 0; k < 12; k++) p[k] = 0.f;
    float cnt[4] = {0.f, 0.f, 0.f, 0.f};
    const int stride = EAS_BLOCKS * 256;
    for (int e = blk * 256 + threadIdx.x; e < N_EDGES; e += stride) {
        int c = ecat[e];
        cnt[0] += (c == 0) ? 1.f : 0.f;
        cnt[1] += (c == 1) ? 1.f : 0.f;
        cnt[2] += (c == 2) ? 1.f : 0.f;
        cnt[3] += (c == 3) ? 1.f : 0.f;
        const float4* v4 = (const float4*)(econt + (size_t)e * 12);
        float4 a = v4[0], bq = v4[1], d = v4[2];
        p[0] += a.x;  p[1] += a.y;  p[2] += a.z;  p[3] += a.w;
        p[4] += bq.x; p[5] += bq.y; p[6] += bq.z; p[7] += bq.w;
        p[8] += d.x;  p[9] += d.y;  p[10] += d.z; p[11] += d.w;
    }
    float vals[16];
#pragma unroll
    for (int k = 0; k < 12; k++) vals[k] = p[k];
#pragma unroll
    for (int k = 0; k < 4; k++) vals[12 + k] = cnt[k];
#pragma unroll
    for (int k = 0; k < 16; k++) {
        float v = vals[k];
#pragma unroll
        for (int off = 32; off > 0; off >>= 1) v += __shfl_xor(v, off);
        vals[k] = v;
    }
    __shared__ float red[4][16];
    int wid = threadIdx.x >> 6, lane = threadIdx.x & 63;
    if (lane == 0) {
#pragma unroll
        for (int k = 0; k < 16; k++) red[wid][k] = vals[k];
    }
    __syncthreads();
    if (threadIdx.x < 16) {
        float s = red[0][threadIdx.x] + red[1][threadIdx.x] +
                  red[2][threadIdx.x] + red[3][threadIdx.x];
        atomicAdd(ea_sum + threadIdx.x, s);
    }
}

__global__ void k_scan(const int* __restrict__ deg, int* __restrict__ rowp,
                       int* __restrict__ cursor) {
    __shared__ int sums[SCAN_T];
    int t = threadIdx.x;
    int lo = t * CHUNK, hi = min(lo + CHUNK, N_NODES);
    int s = 0;
    for (int i = lo; i < hi; i++) s += deg[i];
    sums[t] = s;
    __syncthreads();
    for (int off = 1; off < SCAN_T; off <<= 1) {
        int v = 0;
        if (t >= off) v = sums[t - off];
        __syncthreads();
        if (t >= off) sums[t] += v;
        __syncthreads();
    }
    int run = sums[t] - s;      // exclusive prefix
    for (int i = lo; i < hi; i++) {
        rowp[i] = run;
        cursor[i] = run;
        run += deg[i];
    }
    if (t == SCAN_T - 1) rowp[N_NODES] = sums[SCAN_T - 1];
}

// fill: interleaved meta record {eid, src|cat<<24}
__global__ void k_fill(const int* __restrict__ ei, const int* __restrict__ ecat,
                       int* __restrict__ cursor, int2* __restrict__ csr_m) {
    int e = blockIdx.x * blockDim.x + threadIdx.x;
    if (e >= N_EDGES) return;
    int d = ei[N_EDGES + e];
    int pos = atomicAdd(cursor + d, 1);
    csr_m[pos] = make_int2(e, ei[e] | (ecat[e] << 24));
}

// ======== GINE1 gather (F=36): 4-edge batches, int2 meta ========
__global__ void k_gine1_gather(const int* __restrict__ rowp,
                               const int2* __restrict__ csr_m,
                               const float* __restrict__ econt,
                               const float* __restrict__ edge_emb,
                               const float* __restrict__ W,   // [16,36]
                               const float* __restrict__ b,   // [36]
                               const float* __restrict__ x,
                               float* __restrict__ agg) {
    int i = blockIdx.x * 4 + (threadIdx.x >> 6);
    int lane = threadIdx.x & 63;
    if (i >= N_NODES) return;
    int c = (lane < NODE_IN) ? lane : (NODE_IN - 1);
    float w[12];
#pragma unroll
    for (int k = 0; k < 12; k++) w[k] = W[(4 + k) * NODE_IN + c];
    float tb[4];
#pragma unroll
    for (int q = 0; q < 4; q++) {
        float v = b[c];
#pragma unroll
        for (int k = 0; k < 4; k++) v += edge_emb[q * 4 + k] * W[k * NODE_IN + c];
        tb[q] = v;
    }
    int beg = rfl(rowp[i]), end = rfl(rowp[i + 1]);
    float acc = 0.f;
    int p = beg;
    for (; p + 4 <= end; p += 4) {
        int eid[4], ps4[4];
        float4 A[4], B[4], C4[4];
        float xs[4];
#pragma unroll
        for (int bq = 0; bq < 4; bq++) {
            int2 mm = csr_m[p + bq];
            eid[bq] = rfl(mm.x); ps4[bq] = rfl(mm.y);
            const float4* ec4 = (const float4*)(econt + (size_t)eid[bq] * 12);
            A[bq] = ec4[0]; B[bq] = ec4[1]; C4[bq] = ec4[2];
            xs[bq] = x[(size_t)(ps4[bq] & 0xFFFFFF) * NODE_IN + c];
        }
#pragma unroll
        for (int bq = 0; bq < 4; bq++) {
            int cat = ps4[bq] >> 24;
            float t = sel4(cat, tb[0], tb[1], tb[2], tb[3]);
            t += A[bq].x * w[0] + A[bq].y * w[1] + A[bq].z * w[2] + A[bq].w * w[3];
            t += B[bq].x * w[4] + B[bq].y * w[5] + B[bq].z * w[6] + B[bq].w * w[7];
            t += C4[bq].x * w[8] + C4[bq].y * w[9] + C4[bq].z * w[10] + C4[bq].w * w[11];
            acc += fmaxf(xs[bq] + t, 0.f);
        }
    }
    for (; p < end; ++p) {
        int2 mm = csr_m[p];
        int eid = rfl(mm.x), ps = rfl(mm.y);
        int src = ps & 0xFFFFFF, cat = ps >> 24;
        const float4* ec4 = (const float4*)(econt + (size_t)eid * 12);
        float4 A = ec4[0], B = ec4[1], C4 = ec4[2];
        float t = sel4(cat, tb[0], tb[1], tb[2], tb[3]);
        t += A.x * w[0] + A.y * w[1] + A.z * w[2] + A.w * w[3];
        t += B.x * w[4] + B.y * w[5] + B.z * w[6] + B.w * w[7];
        t += C4.x * w[8] + C4.y * w[9] + C4.z * w[10] + C4.w * w[11];
        acc += fmaxf(x[(size_t)src * NODE_IN + c] + t, 0.f);
    }
    if (lane < NODE_IN) agg[(size_t)i * NODE_IN + lane] = acc;
}

// ===== GINE1 node MLP + BN; OUTPUT h1 as paired bf16 (ch c | ch c+64) =====
__global__ __launch_bounds__(256, 4) void k_gine1_node(
        const float* __restrict__ x, const float* __restrict__ agg,
        const float* __restrict__ eps_p,
        const float* __restrict__ W,   // [36,128]
        const float* __restrict__ b, const float* __restrict__ g,
        const float* __restrict__ bb, const float* __restrict__ m,
        const float* __restrict__ v, unsigned* __restrict__ h1p) {
    __shared__ float sW[NODE_IN * C_HID];     // 18 KB
    __shared__ float sz[DT_NT * NODE_IN];     // 4.5 KB
    int tid = threadIdx.x;
    int node0 = blockIdx.x * DT_NT;
    float eps = eps_p[0];
    {
        const float4* Wv = (const float4*)W;
        float4* sWv = (float4*)sW;
        for (int t = tid; t < NODE_IN * C_HID / 4; t += 256) sWv[t] = Wv[t];
    }
    {
        int nmax = min(DT_NT, N_NODES - node0);
        int tot = nmax * NODE_IN / 4;
        const float4* xv = (const float4*)(x + (size_t)node0 * NODE_IN);
        const float4* av = (const float4*)(agg + (size_t)node0 * NODE_IN);
        float4* szv = (float4*)sz;
        float s = 1.f + eps;
        for (int t = tid; t < tot; t += 256) {
            float4 a = xv[t], c = av[t];
            float4 r;
            r.x = s * a.x + c.x; r.y = s * a.y + c.y;
            r.z = s * a.z + c.z; r.w = s * a.w + c.w;
            szv[t] = r;
        }
    }
    __syncthreads();
    int cg = tid & 15, c0 = cg * 4;           // pair base (lo channels c0..c0+3)
    int n0 = (tid >> 4) * 2;                  // 2 nodes per thread
    float4 bL = *(const float4*)&b[c0];
    float4 bH = *(const float4*)&b[c0 + 64];
    float accL[2][4], accH[2][4];
#pragma unroll
    for (int n = 0; n < 2; n++) {
        accL[n][0] = bL.x; accL[n][1] = bL.y; accL[n][2] = bL.z; accL[n][3] = bL.w;
        accH[n][0] = bH.x; accH[n][1] = bH.y; accH[n][2] = bH.z; accH[n][3] = bH.w;
    }
#pragma unroll 2
    for (int jb = 0; jb < NODE_IN; jb += 4) {
#pragma unroll
        for (int r = 0; r < 4; r++) {
            float4 wl = *(const float4*)&sW[(jb + r) * C_HID + c0];
            float4 wh = *(const float4*)&sW[(jb + r) * C_HID + c0 + 64];
#pragma unroll
            for (int n = 0; n < 2; n++) {
                float zz = sz[(n0 + n) * NODE_IN + jb + r];
                accL[n][0] += zz * wl.x; accL[n][1] += zz * wl.y;
                accL[n][2] += zz * wl.z; accL[n][3] += zz * wl.w;
                accH[n][0] += zz * wh.x; accH[n][1] += zz * wh.y;
                accH[n][2] += zz * wh.z; accH[n][3] += zz * wh.w;
            }
        }
    }
    float4 gL = *(const float4*)&g[c0],  gH = *(const float4*)&g[c0 + 64];
    float4 mL = *(const float4*)&m[c0],  mH = *(const float4*)&m[c0 + 64];
    float4 vL = *(const float4*)&v[c0],  vH = *(const float4*)&v[c0 + 64];
    float4 bbL = *(const float4*)&bb[c0], bbH = *(const float4*)&bb[c0 + 64];
    float scL[4] = { gL.x * rsqrtf(vL.x + BN_EPS), gL.y * rsqrtf(vL.y + BN_EPS),
                     gL.z * rsqrtf(vL.z + BN_EPS), gL.w * rsqrtf(vL.w + BN_EPS) };
    float scH[4] = { gH.x * rsqrtf(vH.x + BN_EPS), gH.y * rsqrtf(vH.y + BN_EPS),
                     gH.z * rsqrtf(vH.z + BN_EPS), gH.w * rsqrtf(vH.w + BN_EPS) };
    float mLa[4] = { mL.x, mL.y, mL.z, mL.w }, mHa[4] = { mH.x, mH.y, mH.z, mH.w };
    float bbLa[4] = { bbL.x, bbL.y, bbL.z, bbL.w }, bbHa[4] = { bbH.x, bbH.y, bbH.z, bbH.w };
#pragma unroll
    for (int n = 0; n < 2; n++) {
        int i = node0 + n0 + n;
        if (i < N_NODES) {
            uint4 o;
            unsigned* po = (unsigned*)&o;
#pragma unroll
            for (int k = 0; k < 4; k++) {
                float lo = (fmaxf(accL[n][k], 0.f) - mLa[k]) * scL[k] + bbLa[k];
                float hi = (fmaxf(accH[n][k], 0.f) - mHa[k]) * scH[k] + bbHa[k];
                po[k] = pack_bf2(lo, hi);
            }
            *(uint4*)&h1p[(size_t)i * 64 + c0] = o;
        }
    }
}

// ======== GINE2 gather: 4-edge batches, paired bf16 h1, packed math ========
__global__ void k_gine2_gather(const int* __restrict__ rowp,
                               const int2* __restrict__ csr_m,
                               const float* __restrict__ econt,
                               const float* __restrict__ edge_emb,
                               const float* __restrict__ W,   // [16,128]
                               const float* __restrict__ b,   // [128]
                               const unsigned* __restrict__ h1p,
                               float2* __restrict__ aggp) {
    int i = blockIdx.x * 4 + (threadIdx.x >> 6);
    int lane = threadIdx.x & 63;
    if (i >= N_NODES) return;
    v2f w01[12];
#pragma unroll
    for (int k = 0; k < 12; k++) {
        w01[k].x = W[(4 + k) * C_HID + lane];
        w01[k].y = W[(4 + k) * C_HID + lane + 64];
    }
    v2f tb01[4];
#pragma unroll
    for (int q = 0; q < 4; q++) {
        v2f t; t.x = b[lane]; t.y = b[lane + 64];
#pragma unroll
        for (int k = 0; k < 4; k++) {
            float ev = edge_emb[q * 4 + k];
            t.x += ev * W[k * C_HID + lane];
            t.y += ev * W[k * C_HID + lane + 64];
        }
        tb01[q] = t;
    }
    const v2f zero = v2(0.f);
    int beg = rfl(rowp[i]), end = rfl(rowp[i + 1]);
    v2f acc01 = zero;
    int p = beg;
    for (; p + 4 <= end; p += 4) {
        int eid[4], ps4[4];
        float4 A[4], B[4], C4[4];
        v2f xs[4];
#pragma unroll
        for (int bq = 0; bq < 4; bq++) {
            int2 mm = csr_m[p + bq];
            eid[bq] = rfl(mm.x); ps4[bq] = rfl(mm.y);
            const float4* ec4 = (const float4*)(econt + (size_t)eid[bq] * 12);
            A[bq] = ec4[0]; B[bq] = ec4[1]; C4[bq] = ec4[2];
            xs[bq] = unpack_bf2(h1p[(size_t)(ps4[bq] & 0xFFFFFF) * 64 + lane]);
        }
#pragma unroll
        for (int bq = 0; bq < 4; bq++) {
            int cat = ps4[bq] >> 24;
            v2f t = sel4v(cat, tb01[0], tb01[1], tb01[2], tb01[3]);
            t = __builtin_elementwise_fma(v2(A[bq].x), w01[0], t);
            t = __builtin_elementwise_fma(v2(A[bq].y), w01[1], t);
            t = __builtin_elementwise_fma(v2(A[bq].z), w01[2], t);
            t = __builtin_elementwise_fma(v2(A[bq].w), w01[3], t);
            t = __builtin_elementwise_fma(v2(B[bq].x), w01[4], t);
            t = __builtin_elementwise_fma(v2(B[bq].y), w01[5], t);
            t = __builtin_elementwise_fma(v2(B[bq].z), w01[6], t);
            t = __builtin_elementwise_fma(v2(B[bq].w), w01[7], t);
            t = __builtin_elementwise_fma(v2(C4[bq].x), w01[8], t);
            t = __builtin_elementwise_fma(v2(C4[bq].y), w01[9], t);
            t = __builtin_elementwise_fma(v2(C4[bq].z), w01[10], t);
            t = __builtin_elementwise_fma(v2(C4[bq].w), w01[11], t);
            acc01 += __builtin_elementwise_max(xs[bq] + t, zero);
        }
    }
    for (; p < end; ++p) {
        int2 mm = csr_m[p];
        int eid = rfl(mm.x), ps = rfl(mm.y);
        int src = ps & 0xFFFFFF, cat = ps >> 24;
        const float4* ec4 = (const float4*)(econt + (size_t)eid * 12);
        float4 A = ec4[0], B = ec4[1], C4 = ec4[2];
        v2f xs = unpack_bf2(h1p[(size_t)src * 64 + lane]);
        v2f t = sel4v(cat, tb01[0], tb01[1], tb01[2], tb01[3]);
        t = __builtin_elementwise_fma(v2(A.x), w01[0], t);
        t = __builtin_elementwise_fma(v2(A.y), w01[1], t);
        t = __builtin_elementwise_fma(v2(A.z), w01[2], t);
        t = __builtin_elementwise_fma(v2(A.w), w01[3], t);
        t = __builtin_elementwise_fma(v2(B.x), w01[4], t);
        t = __builtin_elementwise_fma(v2(B.y), w01[5], t);
        t = __builtin_elementwise_fma(v2(B.z), w01[6], t);
        t = __builtin_elementwise_fma(v2(B.w), w01[7], t);
        t = __builtin_elementwise_fma(v2(C4.x), w01[8], t);
        t = __builtin_elementwise_fma(v2(C4.y), w01[9], t);
        t = __builtin_elementwise_fma(v2(C4.z), w01[10], t);
        t = __builtin_elementwise_fma(v2(C4.w), w01[11], t);
        acc01 += __builtin_elementwise_max(xs + t, zero);
    }
    float2 o; o.x = acc01.x; o.y = acc01.y;
    aggp[(size_t)i * 64 + lane] = o;
}

// ===== GINE2 node MLP + BN; h1 paired bf16 + agg paired fp32 in, h2 standard out =====
__global__ __launch_bounds__(256, 4) void k_gine2_node(
        const unsigned* __restrict__ h1p, const float2* __restrict__ aggp,
        const float* __restrict__ eps_p,
        const float* __restrict__ W,   // [128,128]
        const float* __restrict__ b, const float* __restrict__ g,
        const float* __restrict__ bb, const float* __restrict__ m,
        const float* __restrict__ v, float* __restrict__ h2) {
    __shared__ float sW[64 * C_HID];          // 32 KB (half of W)
    __shared__ float sz[DT_NT * C_HID];       // 16 KB
    int tid = threadIdx.x;
    int node0 = blockIdx.x * DT_NT;
    float eps = eps_p[0];
    {
        int nmax = min(DT_NT, N_NODES - node0);
        int tot = nmax * 64;                  // pairs
        float s = 1.f + eps;
        for (int t = tid; t < tot; t += 256) {
            int n = t >> 6, pp = t & 63;
            v2f h = unpack_bf2(h1p[(size_t)(node0 + n) * 64 + pp]);
            float2 a = aggp[(size_t)(node0 + n) * 64 + pp];
            sz[n * C_HID + pp]      = s * h.x + a.x;
            sz[n * C_HID + pp + 64] = s * h.y + a.y;
        }
    }
    int cg = tid & 31, c0 = cg * 4;
    int n0 = (tid >> 5) * 4;
    float4 bi = *(const float4*)&b[c0];
    float acc[4][4];
#pragma unroll
    for (int n = 0; n < 4; n++) {
        acc[n][0] = bi.x; acc[n][1] = bi.y; acc[n][2] = bi.z; acc[n][3] = bi.w;
    }
    for (int half = 0; half < 2; half++) {
        __syncthreads();
        {
            const float4* Wv = (const float4*)(W + half * 64 * C_HID);
            float4* sWv = (float4*)sW;
            for (int t = tid; t < 64 * C_HID / 4; t += 256) sWv[t] = Wv[t];
        }
        __syncthreads();
        int jbase = half * 64;
#pragma unroll 2
        for (int jb = 0; jb < 64; jb += 4) {
            float4 w0 = *(const float4*)&sW[(jb + 0) * C_HID + c0];
            float4 w1 = *(const float4*)&sW[(jb + 1) * C_HID + c0];
            float4 w2 = *(const float4*)&sW[(jb + 2) * C_HID + c0];
            float4 w3 = *(const float4*)&sW[(jb + 3) * C_HID + c0];
#pragma unroll
            for (int n = 0; n < 4; n++) {
                float4 zz = *(const float4*)&sz[(n0 + n) * C_HID + jbase + jb];
                acc[n][0] += zz.x * w0.x + zz.y * w1.x + zz.z * w2.x + zz.w * w3.x;
                acc[n][1] += zz.x * w0.y + zz.y * w1.y + zz.z * w2.y + zz.w * w3.y;
                acc[n][2] += zz.x * w0.z + zz.y * w1.z + zz.z * w2.z + zz.w * w3.z;
                acc[n][3] += zz.x * w0.w + zz.y * w1.w + zz.z * w2.w + zz.w * w3.w;
            }
        }
    }
    float4 gg = *(const float4*)&g[c0];
    float4 mm = *(const float4*)&m[c0];
    float4 vv = *(const float4*)&v[c0];
    float4 bbv = *(const float4*)&bb[c0];
    float4 sc;
    sc.x = gg.x * rsqrtf(vv.x + BN_EPS); sc.y = gg.y * rsqrtf(vv.y + BN_EPS);
    sc.z = gg.z * rsqrtf(vv.z + BN_EPS); sc.w = gg.w * rsqrtf(vv.w + BN_EPS);
#pragma unroll
    for (int n = 0; n < 4; n++) {
        int i = node0 + n0 + n;
        if (i < N_NODES) {
            float4 o;
            o.x = (fmaxf(acc[n][0], 0.f) - mm.x) * sc.x + bbv.x;
            o.y = (fmaxf(acc[n][1], 0.f) - mm.y) * sc.y + bbv.y;
            o.z = (fmaxf(acc[n][2], 0.f) - mm.z) * sc.z + bbv.z;
            o.w = (fmaxf(acc[n][3], 0.f) - mm.w) * sc.w + bbv.w;
            *(float4*)&h2[(size_t)i * C_HID + c0] = o;
        }
    }
}

// ===== GAT node transforms: xl paired bf16, xr paired fp32; block 0 also
//       computes ee_loop = mean(ea) @ We (consumer is the next kernel) =====
__global__ __launch_bounds__(256, 4) void k_gat0(
        const float* __restrict__ h2,
        const float* __restrict__ Wl, const float* __restrict__ bl,
        const float* __restrict__ Wr, const float* __restrict__ br,
        const float* __restrict__ ea_sum, const float* __restrict__ edge_emb,
        const float* __restrict__ We,
        unsigned* __restrict__ xlp, float2* __restrict__ xrp,
        float* __restrict__ ee_loop) {
    __shared__ float sW[64 * C_HID];          // 32 KB
    __shared__ float sz[DT_NT * C_HID];       // 16 KB
    int tid = threadIdx.x;
    if (blockIdx.x == 0 && tid < C_HID) {
        const float inv = 1.f / (float)N_EDGES;
        float acc = 0.f;
#pragma unroll
        for (int k = 0; k < 4; k++) {
            float s = 0.f;
#pragma unroll
            for (int q = 0; q < 4; q++) s += ea_sum[12 + q] * edge_emb[q * 4 + k];
            acc += (s * inv) * We[k * C_HID + tid];
        }
#pragma unroll
        for (int k = 0; k < 12; k++)
            acc += (ea_sum[k] * inv) * We[(4 + k) * C_HID + tid];
        ee_loop[tid] = acc;
    }
    int node0 = blockIdx.x * DT_NT;
    {
        int nmax = min(DT_NT, N_NODES - node0);
        int tot = nmax * C_HID / 4;
        const float4* hv = (const float4*)(h2 + (size_t)node0 * C_HID);
        float4* szv = (float4*)sz;
        for (int t = tid; t < tot; t += 256) szv[t] = hv[t];
    }
    int cg = tid & 15, c0 = cg * 4;           // pair base
    int n0 = (tid >> 4) * 2;                  // 2 nodes
    for (int wsel = 0; wsel < 2; wsel++) {
        const float* Wm = wsel ? Wr : Wl;
        const float* bm = wsel ? br : bl;
        float4 bL = *(const float4*)&bm[c0];
        float4 bH = *(const float4*)&bm[c0 + 64];
        float accL[2][4], accH[2][4];
#pragma unroll
        for (int n = 0; n < 2; n++) {
            accL[n][0] = bL.x; accL[n][1] = bL.y; accL[n][2] = bL.z; accL[n][3] = bL.w;
            accH[n][0] = bH.x; accH[n][1] = bH.y; accH[n][2] = bH.z; accH[n][3] = bH.w;
        }
        for (int half = 0; half < 2; half++) {
            __syncthreads();
            {
                const float4* Wv = (const float4*)(Wm + half * 64 * C_HID);
                float4* sWv = (float4*)sW;
                for (int t = tid; t < 64 * C_HID / 4; t += 256) sWv[t] = Wv[t];
            }
            __syncthreads();
            int jbase = half * 64;
#pragma unroll 2
            for (int jb = 0; jb < 64; jb += 4) {
#pragma unroll
                for (int r = 0; r < 4; r++) {
                    float4 wl = *(const float4*)&sW[(jb + r) * C_HID + c0];
                    float4 wh = *(const float4*)&sW[(jb + r) * C_HID + c0 + 64];
#pragma unroll
                    for (int n = 0; n < 2; n++) {
                        float zz = sz[(n0 + n) * C_HID + jbase + jb + r];
                        accL[n][0] += zz * wl.x; accL[n][1] += zz * wl.y;
                        accL[n][2] += zz * wl.z; accL[n][3] += zz * wl.w;
                        accH[n][0] += zz * wh.x; accH[n][1] += zz * wh.y;
                        accH[n][2] += zz * wh.z; accH[n][3] += zz * wh.w;
                    }
                }
            }
        }
#pragma unroll
        for (int n = 0; n < 2; n++) {
            int i = node0 + n0 + n;
            if (i < N_NODES) {
                if (wsel == 0) {
                    uint4 o;
                    unsigned* po = (unsigned*)&o;
#pragma unroll
                    for (int k = 0; k < 4; k++) po[k] = pack_bf2(accL[n][k], accH[n][k]);
                    *(uint4*)&xlp[(size_t)i * 64 + c0] = o;
                } else {
                    float4 o1, o2;
                    o1.x = accL[n][0]; o1.y = accH[n][0]; o1.z = accL[n][1]; o1.w = accH[n][1];
                    o2.x = accL[n][2]; o2.y = accH[n][2]; o2.z = accL[n][3]; o2.w = accH[n][3];
                    *(float4*)&xrp[(size_t)i * 64 + c0] = o1;
                    *(float4*)&xrp[(size_t)i * 64 + c0 + 2] = o2;
                }
            }
        }
    }
}

// ===== GAT fused: 4-edge batches, int2 meta, plain-exp softmax, packed math =====
__global__ void k_gat_fused(const int* __restrict__ rowp,
                            const int2* __restrict__ csr_m,
                            const float* __restrict__ econt,
                            const float* __restrict__ edge_emb,
                            const float* __restrict__ We,    // [16,128]
                            const float* __restrict__ att,   // [128]
                            const float* __restrict__ ee_loop,
                            const unsigned* __restrict__ xlp,
                            const float2* __restrict__ xrp,
                            const float* __restrict__ bias,  // [64]
                            float* __restrict__ out) {
    int i = blockIdx.x * 4 + (threadIdx.x >> 6);
    int lane = threadIdx.x & 63;
    if (i >= N_NODES) return;
    v2f w01[12];
#pragma unroll
    for (int k = 0; k < 12; k++) {
        w01[k].x = We[(4 + k) * C_HID + lane];
        w01[k].y = We[(4 + k) * C_HID + lane + 64];
    }
    v2f tb01[4];
#pragma unroll
    for (int q = 0; q < 4; q++) {
        v2f t = v2(0.f);
#pragma unroll
        for (int k = 0; k < 4; k++) {
            float ev = edge_emb[q * 4 + k];
            t.x += ev * We[k * C_HID + lane];
            t.y += ev * We[k * C_HID + lane + 64];
        }
        tb01[q] = t;
    }
    v2f at01; at01.x = att[lane]; at01.y = att[lane + 64];
    v2f lp01; lp01.x = ee_loop[lane]; lp01.y = ee_loop[lane + 64];
    const v2f zero = v2(0.f);
    const v2f fifth = v2(0.2f);

    float2 xr2 = xrp[(size_t)i * 64 + lane];
    v2f xr01; xr01.x = xr2.x; xr01.y = xr2.y;
    v2f xld01 = unpack_bf2(xlp[(size_t)i * 64 + lane]);

    // self-loop alpha (plain exp — alphas bounded, fp32-safe; verified R8)
    v2f z01 = xld01 + xr01 + lp01;
    z01 = __builtin_elementwise_max(z01, zero) +
          fifth * __builtin_elementwise_min(z01, zero);
    v2f d01 = z01 * at01;
#pragma unroll
    for (int off = 32; off > 0; off >>= 1) {
        v2f t;
        t.x = __shfl_xor(d01.x, off);
        t.y = __shfl_xor(d01.y, off);
        d01 += t;
    }
    v2f den01; den01.x = __expf(d01.x); den01.y = __expf(d01.y);
    v2f acc01 = xld01 * den01;

    int beg = rfl(rowp[i]), end = rfl(rowp[i + 1]);
    int p = beg;
    for (; p + 4 <= end; p += 4) {
        int eid[4], ps4[4];
        float4 A[4], B[4], C4[4];
        v2f xs[4];
#pragma unroll
        for (int bq = 0; bq < 4; bq++) {
            int2 mm = csr_m[p + bq];
            eid[bq] = rfl(mm.x); ps4[bq] = rfl(mm.y);
            const float4* ec4 = (const float4*)(econt + (size_t)eid[bq] * 12);
            A[bq] = ec4[0]; B[bq] = ec4[1]; C4[bq] = ec4[2];
            xs[bq] = unpack_bf2(xlp[(size_t)(ps4[bq] & 0xFFFFFF) * 64 + lane]);
        }
        v2f dd[4];
#pragma unroll
        for (int bq = 0; bq < 4; bq++) {
            int cat = ps4[bq] >> 24;
            v2f e = sel4v(cat, tb01[0], tb01[1], tb01[2], tb01[3]);
            e = __builtin_elementwise_fma(v2(A[bq].x), w01[0], e);
            e = __builtin_elementwise_fma(v2(A[bq].y), w01[1], e);
            e = __builtin_elementwise_fma(v2(A[bq].z), w01[2], e);
            e = __builtin_elementwise_fma(v2(A[bq].w), w01[3], e);
            e = __builtin_elementwise_fma(v2(B[bq].x), w01[4], e);
            e = __builtin_elementwise_fma(v2(B[bq].y), w01[5], e);
            e = __builtin_elementwise_fma(v2(B[bq].z), w01[6], e);
            e = __builtin_elementwise_fma(v2(B[bq].w), w01[7], e);
            e = __builtin_elementwise_fma(v2(C4[bq].x), w01[8], e);
            e = __builtin_elementwise_fma(v2(C4[bq].y), w01[9], e);
            e = __builtin_elementwise_fma(v2(C4[bq].z), w01[10], e);
            e = __builtin_elementwise_fma(v2(C4[bq].w), w01[11], e);
            v2f z = xs[bq] + xr01 + e;
            z = __builtin_elementwise_max(z, zero) +
                fifth * __builtin_elementwise_min(z, zero);
            dd[bq] = z * at01;
        }
#pragma unroll
        for (int off = 32; off > 0; off >>= 1) {
#pragma unroll
            for (int bq = 0; bq < 4; bq++) {
                v2f t;
                t.x = __shfl_xor(dd[bq].x, off);
                t.y = __shfl_xor(dd[bq].y, off);
                dd[bq] += t;
            }
        }
        v2f p0; p0.x = __expf(dd[0].x); p0.y = __expf(dd[0].y);
        v2f p1; p1.x = __expf(dd[1].x); p1.y = __expf(dd[1].y);
        v2f p2; p2.x = __expf(dd[2].x); p2.y = __expf(dd[2].y);
        v2f p3; p3.x = __expf(dd[3].x); p3.y = __expf(dd[3].y);
        den01 += (p0 + p1) + (p2 + p3);
        acc01 = __builtin_elementwise_fma(p0, xs[0], acc01);
        acc01 = __builtin_elementwise_fma(p1, xs[1], acc01);
        acc01 = __builtin_elementwise_fma(p2, xs[2], acc01);
        acc01 = __builtin_elementwise_fma(p3, xs[3], acc01);
    }
    for (; p < end; ++p) {
        int2 mm = csr_m[p];
        int eid = rfl(mm.x), ps = rfl(mm.y);
        int src = ps & 0xFFFFFF, cat = ps >> 24;
        const float4* ec4 = (const float4*)(econt + (size_t)eid * 12);
        float4 A = ec4[0], B = ec4[1], C4 = ec4[2];
        v2f xs = unpack_bf2(xlp[(size_t)src * 64 + lane]);
        v2f e = sel4v(cat, tb01[0], tb01[1], tb01[2], tb01[3]);
        e = __builtin_elementwise_fma(v2(A.x), w01[0], e);
        e = __builtin_elementwise_fma(v2(A.y), w01[1], e);
        e = __builtin_elementwise_fma(v2(A.z), w01[2], e);
        e = __builtin_elementwise_fma(v2(A.w), w01[3], e);
        e = __builtin_elementwise_fma(v2(B.x), w01[4], e);
        e = __builtin_elementwise_fma(v2(B.y), w01[5], e);
        e = __builtin_elementwise_fma(v2(B.z), w01[6], e);
        e = __builtin_elementwise_fma(v2(B.w), w01[7], e);
        e = __builtin_elementwise_fma(v2(C4.x), w01[8], e);
        e = __builtin_elementwise_fma(v2(C4.y), w01[9], e);
        e = __builtin_elementwise_fma(v2(C4.z), w01[10], e);
        e = __builtin_elementwise_fma(v2(C4.w), w01[11], e);
        v2f z = xs + xr01 + e;
        z = __builtin_elementwise_max(z, zero) +
            fifth * __builtin_elementwise_min(z, zero);
        v2f a = z * at01;
#pragma unroll
        for (int off = 32; off > 0; off >>= 1) {
            v2f t;
            t.x = __shfl_xor(a.x, off);
            t.y = __shfl_xor(a.y, off);
            a += t;
        }
        v2f pe; pe.x = __expf(a.x); pe.y = __expf(a.y);
        den01 += pe;
        acc01 = __builtin_elementwise_fma(pe, xs, acc01);
    }
    out[(size_t)i * C_OUT + lane] =
        0.5f * (acc01.x / den01.x + acc01.y / den01.y) + bias[lane];
}

extern "C" void kernel_launch(void* const* d_in, const int* in_sizes, int n_in,
                              void* d_out, int out_size, void* d_ws, size_t ws_size,
                              hipStream_t stream) {
    const int*   x_cat    = (const int*)d_in[0];
    const float* x_cont   = (const float*)d_in[1];
    const int*   e_cat    = (const int*)d_in[2];
    const float* e_cont   = (const float*)d_in[3];
    const int*   ei       = (const int*)d_in[4];
    const float* node_emb = (const float*)d_in[5];
    const float* edge_emb = (const float*)d_in[6];
    const float* eps1     = (const float*)d_in[7];
    const float* W1e      = (const float*)d_in[8];
    const float* b1e      = (const float*)d_in[9];
    const float* W1n      = (const float*)d_in[10];
    const float* b1n      = (const float*)d_in[11];
    const float* g1       = (const float*)d_in[12];
    const float* bb1      = (const float*)d_in[13];
    const float* m1       = (const float*)d_in[14];
    const float* v1       = (const float*)d_in[15];
    const float* eps2     = (const float*)d_in[16];
    const float* W2e      = (const float*)d_in[17];
    const float* b2e      = (const float*)d_in[18];
    const float* W2n      = (const float*)d_in[19];
    const float* b2n      = (const float*)d_in[20];
    const float* g2       = (const float*)d_in[21];
    const float* bb2      = (const float*)d_in[22];
    const float* m2       = (const float*)d_in[23];
    const float* v2p      = (const float*)d_in[24];
    const float* Wl       = (const float*)d_in[25];
    const float* bl       = (const float*)d_in[26];
    const float* Wr       = (const float*)d_in[27];
    const float* br       = (const float*)d_in[28];
    const float* Weg      = (const float*)d_in[29];
    const float* att      = (const float*)d_in[30];
    const float* gbias    = (const float*)d_in[31];

    const size_t NF128 = (size_t)N_NODES * C_HID;

    // layout: A (fp32, x -> h2) | B (fp32, agg36 / agg-pairs / xr-pairs) | Hb (bf16 pairs)
    float* A = (float*)d_ws;                 // N*128 floats
    float* B = A + NF128;                    // N*128 floats
    unsigned* Hb = (unsigned*)(B + NF128);   // N*64 u32
    float* ea_sum  = (float*)(Hb + (size_t)N_NODES * 64);   // 16
    float* ee_loop = ea_sum + 16;            // 128
    int2* csr_m  = (int2*)(ee_loop + C_HID); // E int2 (8B-aligned: even float count)
    int* deg     = (int*)(csr_m + N_EDGES);  // N
    int* cursor  = deg + N_NODES;            // N
    int* rowp    = cursor + N_NODES;         // N+1

    float* x = A;                 // N*36 (dead before h2 written)
    float* h2 = A;
    float* agg36 = B;
    float2* aggp = (float2*)B;    // N*64 float2
    float2* xrp  = (float2*)B;
    unsigned* h1p = Hb; unsigned* xlp = Hb;

    size_t need = (size_t)((char*)(rowp + N_NODES + 1) - (char*)d_ws);
    if (ws_size < need) return;

    hipMemsetAsync(deg, 0, N_NODES * sizeof(int), stream);
    hipMemsetAsync(ea_sum, 0, 16 * sizeof(float), stream);

    const int EB = (N_EDGES + 255) / 256;
    const int NB4 = (N_NODES + 3) / 4;
    const int NBD = (N_NODES + DT_NT - 1) / DT_NT;

    k_prep<<<NF_BLOCKS + DEG_BLOCKS + EAS_BLOCKS, 256, 0, stream>>>(
        x_cat, x_cont, node_emb, ei, e_cat, e_cont, x, deg, ea_sum);
    k_scan<<<1, SCAN_T, 0, stream>>>(deg, rowp, cursor);
    k_fill<<<EB, 256, 0, stream>>>(ei, e_cat, cursor, csr_m);

    k_gine1_gather<<<NB4, 256, 0, stream>>>(
        rowp, csr_m, e_cont, edge_emb, W1e, b1e, x, agg36);
    k_gine1_node<<<NBD, 256, 0, stream>>>(
        x, agg36, eps1, W1n, b1n, g1, bb1, m1, v1, h1p);
    k_gine2_gather<<<NB4, 256, 0, stream>>>(
        rowp, csr_m, e_cont, edge_emb, W2e, b2e, h1p, aggp);
    k_gine2_node<<<NBD, 256, 0, stream>>>(
        h1p, aggp, eps2, W2n, b2n, g2, bb2, m2, v2p, h2);

    k_gat0<<<NBD, 256, 0, stream>>>(
        h2, Wl, bl, Wr, br, ea_sum, edge_emb, Weg, xlp, xrp, ee_loop);
    k_gat_fused<<<NB4, 256, 0, stream>>>(
        rowp, csr_m, e_cont, edge_emb, Weg, att, ee_loop,
        xlp, xrp, gbias, (float*)d_out);
}